// Round 1
// baseline (808.339 us; speedup 1.0000x reference)
//
#include <hip/hip_runtime.h>

#define PAD_IDX 1
#define BATCH 32
#define TLEN 64
#define SLEN 400
#define CVOCAB 100
#define DDIM 512
#define VOCAB 32000
#define ROWS (BATCH * TLEN)        // 2048
#define OUTC (VOCAB + CVOCAB)      // 32100

typedef float f32x4 __attribute__((ext_vector_type(4)));
typedef __bf16 bf16x8 __attribute__((ext_vector_type(8)));

__device__ __forceinline__ unsigned short f32_to_bf16_rne(float f) {
    union { float f; unsigned u; } x; x.f = f;
    return (unsigned short)((x.u + 0x7FFFu + ((x.u >> 16) & 1u)) >> 16);
}

// ---------------- hidden f32 -> bf16 (2048x512) ----------------
__global__ void k_convert_hidden(const float* __restrict__ hid,
                                 unsigned short* __restrict__ a_bf) {
    int i = blockIdx.x * 256 + threadIdx.x;           // 262144 float4 groups
    const float4 v = reinterpret_cast<const float4*>(hid)[i];
    ushort4 o;
    o.x = f32_to_bf16_rne(v.x); o.y = f32_to_bf16_rne(v.y);
    o.z = f32_to_bf16_rne(v.z); o.w = f32_to_bf16_rne(v.w);
    reinterpret_cast<ushort4*>(a_bf)[i] = o;
}

// ---------------- W [512][32000] f32 -> W^T [32000][512] bf16 ----------------
__global__ void k_transpose_w(const float* __restrict__ W,
                              unsigned short* __restrict__ Wt) {
    __shared__ float tile[32][33];
    const int nx = threadIdx.x;        // 0..31
    const int ky = threadIdx.y;        // 0..7
    const int n0 = blockIdx.x * 32;
    const int k0 = blockIdx.y * 32;
#pragma unroll
    for (int j = 0; j < 4; ++j)
        tile[ky + 8 * j][nx] = W[(k0 + ky + 8 * j) * VOCAB + n0 + nx];
    __syncthreads();
#pragma unroll
    for (int j = 0; j < 4; ++j) {
        int n = ky + 8 * j;
        Wt[(n0 + n) * DDIM + k0 + nx] = f32_to_bf16_rne(tile[nx][n]);
    }
}

// ---------------- p_copy = sigmoid(hidden @ Wc + bc); zero row_sum ----------------
__global__ void k_pcopy(const float* __restrict__ hid, const float* __restrict__ Wc,
                        const float* __restrict__ bc, float* __restrict__ p_copy,
                        float* __restrict__ row_sum) {
    const int tid = threadIdx.x;
    const int lane = tid & 63;
    const int wv = tid >> 6;
    const int r = blockIdx.x * 4 + wv;
    float s = 0.f;
#pragma unroll
    for (int j = 0; j < 8; ++j)
        s += hid[r * DDIM + lane + 64 * j] * Wc[lane + 64 * j];
#pragma unroll
    for (int off = 32; off >= 1; off >>= 1)
        s += __shfl_xor(s, off);
    if (lane == 0) {
        float z = s + bc[0];
        p_copy[r] = 1.f / (1.f + __expf(-z));
        row_sum[r] = 0.f;
    }
}

// ---------------- GEMM: out[:, :32000] = exp(A @ Wt^T + b) (PAD masked),
//                  row_sum += partial sums.  m97-style, 128x128x64, swizzled LDS.
__global__ void k_gemm_exp(const unsigned short* __restrict__ A,   // [2048][512] bf16
                           const unsigned short* __restrict__ Bt,  // [32000][512] bf16
                           const float* __restrict__ bias,         // [32000]
                           float* __restrict__ out,                // [2048][32100]
                           float* __restrict__ row_sum) {
    __shared__ __align__(16) unsigned short ldsA[128 * 64];
    __shared__ __align__(16) unsigned short ldsB[128 * 64];

    const int tid = threadIdx.x;
    const int lane = tid & 63;
    const int wv = tid >> 6;           // 0..3
    const int wm = wv >> 1, wn = wv & 1;
    const int m0 = blockIdx.y * 128;
    const int n0 = blockIdx.x * 128;
    const int g = lane >> 4;           // 0..3
    const int c16 = lane & 15;

    f32x4 acc[4][4];
#pragma unroll
    for (int mi = 0; mi < 4; ++mi)
#pragma unroll
        for (int ni = 0; ni < 4; ++ni)
            acc[mi][ni] = (f32x4){0.f, 0.f, 0.f, 0.f};

    for (int ks = 0; ks < 8; ++ks) {
        const int k0 = ks * 64;
        // stage A and B tiles: 1024 chunks of 16B each, seg-swizzled on the global side
#pragma unroll
        for (int it = 0; it < 4; ++it) {
            const int ci = it * 256 + wv * 64 + lane;
            const int row = ci >> 3;
            const int seg = (ci & 7) ^ (row & 7);
            const unsigned short* gA = A + (m0 + row) * DDIM + k0 + seg * 8;
            const unsigned short* gB = Bt + (n0 + row) * DDIM + k0 + seg * 8;
            __builtin_amdgcn_global_load_lds(
                (const __attribute__((address_space(1))) void*)gA,
                (__attribute__((address_space(3))) void*)(ldsA + (it * 256 + wv * 64) * 8),
                16, 0, 0);
            __builtin_amdgcn_global_load_lds(
                (const __attribute__((address_space(1))) void*)gB,
                (__attribute__((address_space(3))) void*)(ldsB + (it * 256 + wv * 64) * 8),
                16, 0, 0);
        }
        __syncthreads();
#pragma unroll
        for (int kk = 0; kk < 2; ++kk) {
            bf16x8 af[4], bf[4];
#pragma unroll
            for (int mi = 0; mi < 4; ++mi) {
                const int row = wm * 64 + mi * 16 + c16;
                const int s16 = (kk * 4 + g) ^ (row & 7);
                af[mi] = *reinterpret_cast<const bf16x8*>(ldsA + row * 64 + s16 * 8);
            }
#pragma unroll
            for (int ni = 0; ni < 4; ++ni) {
                const int row = wn * 64 + ni * 16 + c16;
                const int s16 = (kk * 4 + g) ^ (row & 7);
                bf[ni] = *reinterpret_cast<const bf16x8*>(ldsB + row * 64 + s16 * 8);
            }
#pragma unroll
            for (int mi = 0; mi < 4; ++mi)
#pragma unroll
                for (int ni = 0; ni < 4; ++ni)
                    acc[mi][ni] = __builtin_amdgcn_mfma_f32_16x16x32_bf16(
                        af[mi], bf[ni], acc[mi][ni], 0, 0, 0);
        }
        __syncthreads();
    }

    // epilogue: bias, PAD mask, exp, store, per-row partial sums
    float bias_v[4];
    int gcol[4];
#pragma unroll
    for (int ni = 0; ni < 4; ++ni) {
        gcol[ni] = n0 + wn * 64 + ni * 16 + c16;
        bias_v[ni] = bias[gcol[ni]];
    }
    float part[4][4];
#pragma unroll
    for (int mi = 0; mi < 4; ++mi)
#pragma unroll
        for (int v = 0; v < 4; ++v)
            part[mi][v] = 0.f;

#pragma unroll
    for (int mi = 0; mi < 4; ++mi) {
#pragma unroll
        for (int ni = 0; ni < 4; ++ni) {
#pragma unroll
            for (int v = 0; v < 4; ++v) {
                const int grow = m0 + wm * 64 + mi * 16 + g * 4 + v;
                float val = acc[mi][ni][v] + bias_v[ni];
                val = (gcol[ni] == PAD_IDX) ? 0.f : __expf(val);
                out[grow * OUTC + gcol[ni]] = val;
                part[mi][v] += val;
            }
        }
    }
#pragma unroll
    for (int mi = 0; mi < 4; ++mi) {
#pragma unroll
        for (int v = 0; v < 4; ++v) {
            float p = part[mi][v];
            p += __shfl_xor(p, 1);
            p += __shfl_xor(p, 2);
            p += __shfl_xor(p, 4);
            p += __shfl_xor(p, 8);
            if (c16 == 0)
                atomicAdd(&row_sum[m0 + wm * 64 + mi * 16 + g * 4 + v], p);
        }
    }
}

// ---------------- in-place scale of out[:, :32000] by (1-p_copy)/row_sum ----------------
__global__ void k_scale(float* __restrict__ out, const float* __restrict__ p_copy,
                        const float* __restrict__ row_sum) {
    const int r = blockIdx.y;
    const int c4 = blockIdx.x * 256 + threadIdx.x;
    if (c4 >= VOCAB / 4) return;
    const float s = (1.f - p_copy[r]) / row_sum[r];
    float4* p = reinterpret_cast<float4*>(out + (size_t)r * OUTC) + c4;
    float4 v = *p;
    v.x *= s; v.y *= s; v.z *= s; v.w *= s;
    *p = v;
}

// ---------------- copy region: out[r, 32000+c] = p_copy[r] * sum_s attn[r,s]*src_map[s, r%32, c]
__global__ void k_copy(const float* __restrict__ attn, const float* __restrict__ src_map,
                       const float* __restrict__ p_copy, float* __restrict__ out) {
    const int tid = threadIdx.x;
    const int lane = tid & 63;
    const int wv = tid >> 6;
    const int r = blockIdx.x * 4 + wv;
    const int b = r & (BATCH - 1);
    float acc0 = 0.f, acc1 = 0.f;
    const float* srcb = src_map + b * CVOCAB;
    const float* arow = attn + r * SLEN;
    for (int s0 = 0; s0 < SLEN; s0 += 64) {
        const float av = (s0 + lane < SLEN) ? arow[s0 + lane] : 0.f;
        const int lim = min(64, SLEN - s0);
        for (int i = 0; i < lim; ++i) {
            const float a = __shfl(av, i);
            const float* sp = srcb + (size_t)(s0 + i) * (BATCH * CVOCAB);
            acc0 += a * sp[lane];
            if (lane < CVOCAB - 64) acc1 += a * sp[lane + 64];
        }
    }
    const float pc = p_copy[r];
    float* orow = out + (size_t)r * OUTC + VOCAB;
    orow[lane] = pc * acc0;                       // lane < 64 < 100
    if (lane + 64 < CVOCAB) orow[lane + 64] = pc * acc1;
}

extern "C" void kernel_launch(void* const* d_in, const int* in_sizes, int n_in,
                              void* d_out, int out_size, void* d_ws, size_t ws_size,
                              hipStream_t stream) {
    const float* hidden = (const float*)d_in[0];
    const float* attn   = (const float*)d_in[1];
    const float* srcmap = (const float*)d_in[2];
    const float* W      = (const float*)d_in[3];
    const float* bias   = (const float*)d_in[4];
    const float* Wc     = (const float*)d_in[5];
    const float* bc     = (const float*)d_in[6];
    float* out = (float*)d_out;

    char* ws = (char*)d_ws;
    size_t off = 0;
    unsigned short* a_bf = (unsigned short*)(ws + off); off += (size_t)ROWS * DDIM * 2;
    unsigned short* wt   = (unsigned short*)(ws + off); off += (size_t)VOCAB * DDIM * 2;
    float* p_copy = (float*)(ws + off); off += (size_t)ROWS * 4;
    float* row_sum = (float*)(ws + off); off += (size_t)ROWS * 4;
    if (ws_size < off) return;   // insufficient workspace — fail loudly via absmax

    k_convert_hidden<<<(ROWS * DDIM / 4 + 255) / 256, 256, 0, stream>>>(hidden, a_bf);
    k_transpose_w<<<dim3(VOCAB / 32, DDIM / 32), dim3(32, 8), 0, stream>>>(W, wt);
    k_pcopy<<<ROWS / 4, 256, 0, stream>>>(hidden, Wc, bc, p_copy, row_sum);
    k_gemm_exp<<<dim3(VOCAB / 128, ROWS / 128), 256, 0, stream>>>(a_bf, wt, bias, out, row_sum);
    k_scale<<<dim3((VOCAB / 4 + 255) / 256, ROWS), 256, 0, stream>>>(out, p_copy, row_sum);
    k_copy<<<ROWS / 4, 256, 0, stream>>>(attn, srcmap, p_copy, out);
}

// Round 3
// 661.039 us; speedup vs baseline: 1.2228x; 1.2228x over previous
//
#include <hip/hip_runtime.h>

#define PAD_IDX 1
#define BATCH 32
#define TLEN 64
#define SLEN 400
#define CVOCAB 100
#define DDIM 512
#define VOCAB 32000
#define ROWS (BATCH * TLEN)        // 2048
#define OUTC (VOCAB + CVOCAB)      // 32100

typedef float f32x4 __attribute__((ext_vector_type(4)));
typedef __bf16 bf16x8 __attribute__((ext_vector_type(8)));

__device__ __forceinline__ unsigned short f32_to_bf16_rne(float f) {
    union { float f; unsigned u; } x; x.f = f;
    return (unsigned short)((x.u + 0x7FFFu + ((x.u >> 16) & 1u)) >> 16);
}
__device__ __forceinline__ float bf16_to_f32(unsigned short h) {
    union { unsigned u; float f; } x; x.u = ((unsigned)h) << 16;
    return x.f;
}

// ---------------- hidden f32 -> bf16 (2048x512) ----------------
__global__ void k_convert_hidden(const float* __restrict__ hid,
                                 unsigned short* __restrict__ a_bf) {
    int i = blockIdx.x * 256 + threadIdx.x;
    const float4 v = reinterpret_cast<const float4*>(hid)[i];
    ushort4 o;
    o.x = f32_to_bf16_rne(v.x); o.y = f32_to_bf16_rne(v.y);
    o.z = f32_to_bf16_rne(v.z); o.w = f32_to_bf16_rne(v.w);
    reinterpret_cast<ushort4*>(a_bf)[i] = o;
}

// ---------------- W [512][32000] f32 -> W^T [32000][512] bf16 ----------------
__global__ void k_transpose_w(const float* __restrict__ W,
                              unsigned short* __restrict__ Wt) {
    __shared__ float tile[32][33];
    const int nx = threadIdx.x;        // 0..31
    const int ky = threadIdx.y;        // 0..7
    const int n0 = blockIdx.x * 32;
    const int k0 = blockIdx.y * 32;
#pragma unroll
    for (int j = 0; j < 4; ++j)
        tile[ky + 8 * j][nx] = W[(k0 + ky + 8 * j) * VOCAB + n0 + nx];
    __syncthreads();
#pragma unroll
    for (int j = 0; j < 4; ++j) {
        int n = ky + 8 * j;
        Wt[(n0 + n) * DDIM + k0 + nx] = f32_to_bf16_rne(tile[nx][n]);
    }
}

// ---------------- p_copy = sigmoid(hidden @ Wc + bc) ----------------
__global__ void k_pcopy(const float* __restrict__ hid, const float* __restrict__ Wc,
                        const float* __restrict__ bc, float* __restrict__ p_copy) {
    const int tid = threadIdx.x;
    const int lane = tid & 63;
    const int wv = tid >> 6;
    const int r = blockIdx.x * 4 + wv;
    float s = 0.f;
#pragma unroll
    for (int j = 0; j < 8; ++j)
        s += hid[r * DDIM + lane + 64 * j] * Wc[lane + 64 * j];
#pragma unroll
    for (int off = 32; off >= 1; off >>= 1)
        s += __shfl_xor(s, off);
    if (lane == 0) {
        float z = s + bc[0];
        p_copy[r] = 1.f / (1.f + __expf(-z));
    }
}

// ---------------- GEMM: bf16 logits (A@Wt^T + b) -> front of each out row.
// 128x128x64 tiles, swizzled LDS, XCD-chunked block mapping.
__global__ void k_gemm(const unsigned short* __restrict__ A,   // [2048][512] bf16
                       const unsigned short* __restrict__ Bt,  // [32000][512] bf16
                       const float* __restrict__ bias,         // [32000]
                       float* __restrict__ out) {               // rows: bf16 logits in bytes [0,64000)
    __shared__ __align__(16) unsigned short ldsA[128 * 64];
    __shared__ __align__(16) unsigned short ldsB[128 * 64];

    const int tid = threadIdx.x;
    const int lane = tid & 63;
    const int wv = tid >> 6;           // 0..3
    const int wm = wv >> 1, wn = wv & 1;

    // XCD-chunked swizzle: 4000 blocks = 8 XCD * 500; within an XCD, m varies
    // fastest so 16 consecutive same-XCD blocks share one B-tile (L2-hot).
    const int bid = blockIdx.x;
    const int lin = (bid & 7) * 500 + (bid >> 3);
    const int m0 = (lin & 15) * 128;
    const int n0 = (lin >> 4) * 128;

    const int g = lane >> 4;           // 0..3
    const int c16 = lane & 15;

    f32x4 acc[4][4];
#pragma unroll
    for (int mi = 0; mi < 4; ++mi)
#pragma unroll
        for (int ni = 0; ni < 4; ++ni)
            acc[mi][ni] = (f32x4){0.f, 0.f, 0.f, 0.f};

    for (int ks = 0; ks < 8; ++ks) {
        const int k0 = ks * 64;
#pragma unroll
        for (int it = 0; it < 4; ++it) {
            const int ci = it * 256 + wv * 64 + lane;
            const int row = ci >> 3;
            const int seg = (ci & 7) ^ (row & 7);
            const unsigned short* gA = A + (m0 + row) * DDIM + k0 + seg * 8;
            const unsigned short* gB = Bt + (n0 + row) * DDIM + k0 + seg * 8;
            __builtin_amdgcn_global_load_lds(
                (const __attribute__((address_space(1))) void*)gA,
                (__attribute__((address_space(3))) void*)(ldsA + (it * 256 + wv * 64) * 8),
                16, 0, 0);
            __builtin_amdgcn_global_load_lds(
                (const __attribute__((address_space(1))) void*)gB,
                (__attribute__((address_space(3))) void*)(ldsB + (it * 256 + wv * 64) * 8),
                16, 0, 0);
        }
        __syncthreads();
#pragma unroll
        for (int kk = 0; kk < 2; ++kk) {
            bf16x8 af[4], bf[4];
#pragma unroll
            for (int mi = 0; mi < 4; ++mi) {
                const int row = wm * 64 + mi * 16 + c16;
                const int s16 = (kk * 4 + g) ^ (row & 7);
                af[mi] = *reinterpret_cast<const bf16x8*>(ldsA + row * 64 + s16 * 8);
            }
#pragma unroll
            for (int ni = 0; ni < 4; ++ni) {
                const int row = wn * 64 + ni * 16 + c16;
                const int s16 = (kk * 4 + g) ^ (row & 7);
                bf[ni] = *reinterpret_cast<const bf16x8*>(ldsB + row * 64 + s16 * 8);
            }
#pragma unroll
            for (int mi = 0; mi < 4; ++mi)
#pragma unroll
                for (int ni = 0; ni < 4; ++ni)
                    acc[mi][ni] = __builtin_amdgcn_mfma_f32_16x16x32_bf16(
                        af[mi], bf[ni], acc[mi][ni], 0, 0, 0);
        }
        __syncthreads();
    }

    // epilogue: bias, convert to bf16, store into out rows (ushort view).
    unsigned short* outu = reinterpret_cast<unsigned short*>(out);
    float bias_v[4];
    int gcol[4];
#pragma unroll
    for (int ni = 0; ni < 4; ++ni) {
        gcol[ni] = n0 + wn * 64 + ni * 16 + c16;
        bias_v[ni] = bias[gcol[ni]];
    }
#pragma unroll
    for (int mi = 0; mi < 4; ++mi) {
#pragma unroll
        for (int v = 0; v < 4; ++v) {
            const size_t rbase = (size_t)(m0 + wm * 64 + mi * 16 + g * 4 + v) * (OUTC * 2);
#pragma unroll
            for (int ni = 0; ni < 4; ++ni)
                outu[rbase + gcol[ni]] = f32_to_bf16_rne(acc[mi][ni][v] + bias_v[ni]);
        }
    }
}

// ---------------- per-row softmax+scale: read bf16 logits (front of row),
// LDS-stage (full 64000 B!), sum exp (PAD excluded), write f32 row in place.
__global__ void __launch_bounds__(512) k_rowsoft(float* __restrict__ out,
                                                 const float* __restrict__ p_copy) {
    __shared__ __align__(16) unsigned short srow[VOCAB];   // 64000 B = 4000 x 16B
    __shared__ float red[8];
    const int tid = threadIdx.x;
    const int r = blockIdx.x;
    const uint4* lrow = reinterpret_cast<const uint4*>(out + (size_t)r * OUTC);
    uint4* srow16 = reinterpret_cast<uint4*>(srow);

    // stage 4000 x 16B chunks: 2000 iters x 2 chunks (512 threads, idx<2000)
#pragma unroll
    for (int it = 0; it < 4; ++it) {
        const int idx = it * 512 + tid;
        if (idx < 2000) {
            srow16[idx * 2]     = lrow[idx * 2];
            srow16[idx * 2 + 1] = lrow[idx * 2 + 1];
        }
    }
    __syncthreads();

    float ps = 0.f;
#pragma unroll
    for (int it = 0; it < 4; ++it) {
        const int idx = it * 512 + tid;
        if (idx < 2000) {
            const int c0 = idx * 16;
#pragma unroll
            for (int j = 0; j < 16; ++j) {
                const int c = c0 + j;
                const float l = bf16_to_f32(srow[c]);
                ps += (c == PAD_IDX) ? 0.f : __expf(l);
            }
        }
    }
#pragma unroll
    for (int off = 32; off >= 1; off >>= 1)
        ps += __shfl_xor(ps, off);
    if ((tid & 63) == 0) red[tid >> 6] = ps;
    __syncthreads();
    float sum = 0.f;
#pragma unroll
    for (int w = 0; w < 8; ++w) sum += red[w];

    const float scale = (1.f - p_copy[r]) / sum;
    float* orow = out + (size_t)r * OUTC;
#pragma unroll
    for (int it = 0; it < 4; ++it) {
        const int idx = it * 512 + tid;
        if (idx < 2000) {
            const int c0 = idx * 16;
#pragma unroll
            for (int q = 0; q < 4; ++q) {
                float4 o;
                float* po = &o.x;
#pragma unroll
                for (int j = 0; j < 4; ++j) {
                    const int c = c0 + q * 4 + j;
                    const float l = bf16_to_f32(srow[c]);
                    po[j] = (c == PAD_IDX) ? 0.f : __expf(l) * scale;
                }
                reinterpret_cast<float4*>(orow + c0)[q] = o;
            }
        }
    }
}

// ---------------- copy region ----------------
__global__ void k_copy(const float* __restrict__ attn, const float* __restrict__ src_map,
                       const float* __restrict__ p_copy, float* __restrict__ out) {
    const int tid = threadIdx.x;
    const int lane = tid & 63;
    const int wv = tid >> 6;
    const int r = blockIdx.x * 4 + wv;
    const int b = r & (BATCH - 1);
    float acc0 = 0.f, acc1 = 0.f;
    const float* srcb = src_map + b * CVOCAB;
    const float* arow = attn + r * SLEN;
    for (int s0 = 0; s0 < SLEN; s0 += 64) {
        const float av = (s0 + lane < SLEN) ? arow[s0 + lane] : 0.f;
        const int lim = min(64, SLEN - s0);
#pragma unroll 8
        for (int i = 0; i < lim; ++i) {
            const float a = __shfl(av, i);
            const float* sp = srcb + (size_t)(s0 + i) * (BATCH * CVOCAB);
            acc0 += a * sp[lane];
            if (lane < CVOCAB - 64) acc1 += a * sp[lane + 64];
        }
    }
    const float pc = p_copy[r];
    float* orow = out + (size_t)r * OUTC + VOCAB;
    orow[lane] = pc * acc0;
    if (lane + 64 < CVOCAB) orow[lane + 64] = pc * acc1;
}

extern "C" void kernel_launch(void* const* d_in, const int* in_sizes, int n_in,
                              void* d_out, int out_size, void* d_ws, size_t ws_size,
                              hipStream_t stream) {
    const float* hidden = (const float*)d_in[0];
    const float* attn   = (const float*)d_in[1];
    const float* srcmap = (const float*)d_in[2];
    const float* W      = (const float*)d_in[3];
    const float* bias   = (const float*)d_in[4];
    const float* Wc     = (const float*)d_in[5];
    const float* bc     = (const float*)d_in[6];
    float* out = (float*)d_out;

    char* ws = (char*)d_ws;
    size_t off = 0;
    unsigned short* a_bf = (unsigned short*)(ws + off); off += (size_t)ROWS * DDIM * 2;
    unsigned short* wt   = (unsigned short*)(ws + off); off += (size_t)VOCAB * DDIM * 2;
    float* p_copy = (float*)(ws + off); off += (size_t)ROWS * 4;
    if (ws_size < off) return;

    k_convert_hidden<<<(ROWS * DDIM / 4 + 255) / 256, 256, 0, stream>>>(hidden, a_bf);
    k_transpose_w<<<dim3(VOCAB / 32, DDIM / 32), dim3(32, 8), 0, stream>>>(W, wt);
    k_pcopy<<<ROWS / 4, 256, 0, stream>>>(hidden, Wc, bc, p_copy);
    k_gemm<<<4000, 256, 0, stream>>>(a_bf, wt, bias, out);
    k_rowsoft<<<ROWS, 512, 0, stream>>>(out, p_copy);
    k_copy<<<ROWS / 4, 256, 0, stream>>>(attn, srcmap, p_copy, out);
}